// Round 9
// baseline (258.607 us; speedup 1.0000x reference)
//
#include <hip/hip_runtime.h>

#define S_ 1024
#define H_ 12
#define DH_ 64
#define D_ 768
#define B_ 2
#define BH_ 24
#define OUTSZ_ (B_*S_*D_)

typedef short bf16x8 __attribute__((ext_vector_type(8)));
typedef float f32x4 __attribute__((ext_vector_type(4)));

#define MFMA16(a,b,c) __builtin_amdgcn_mfma_f32_16x16x32_bf16(a,b,c,0,0,0)

__device__ __forceinline__ short f2bf(float x){
  union { float f; unsigned u; } v; v.f = x;
  unsigned r = (v.u + 0x7FFFu + ((v.u>>16)&1u)) >> 16;
  return (short)r;
}
__device__ __forceinline__ float bf2f(short s){
  union { unsigned u; float f; } v; v.u = ((unsigned)(unsigned short)s) << 16;
  return v.f;
}
__device__ __forceinline__ unsigned pack2(short a, short b){
  return ((unsigned)(unsigned short)a) | (((unsigned)(unsigned short)b) << 16);
}
__device__ __forceinline__ uint4 pack8(float4 a, float4 b){
  uint4 r;
  r.x = pack2(f2bf(a.x), f2bf(a.y));
  r.y = pack2(f2bf(a.z), f2bf(a.w));
  r.z = pack2(f2bf(b.x), f2bf(b.y));
  r.w = pack2(f2bf(b.z), f2bf(b.w));
  return r;
}
__device__ __forceinline__ short4 cvt4(float4 x){
  short4 o; o.x=f2bf(x.x); o.y=f2bf(x.y); o.z=f2bf(x.z); o.w=f2bf(x.w);
  return o;
}

// ---------- P0a: convert q_in/k_in/v_in fp32 -> bf16 ----------
__global__ __launch_bounds__(256) void cvt_in_kernel(
    const float* __restrict__ q, const float* __restrict__ k, const float* __restrict__ v,
    short* __restrict__ aq, short* __restrict__ ak, short* __restrict__ av)
{
    const float* src = blockIdx.y==0 ? q : (blockIdx.y==1 ? k : v);
    short* dst       = blockIdx.y==0 ? aq : (blockIdx.y==1 ? ak : av);
    size_t i = ((size_t)blockIdx.x*256 + threadIdx.x)*4;
    float4 x = *(const float4*)&src[i];
    *(short4*)&dst[i] = cvt4(x);
}

// ---------- P0b: transpose+convert W[k][n] fp32 -> WT[n][k] bf16 ----------
__global__ __launch_bounds__(256) void wt_kernel(
    const float* __restrict__ Wq, const float* __restrict__ Wk,
    const float* __restrict__ Wv, const float* __restrict__ Wo,
    short* __restrict__ Tq, short* __restrict__ Tk, short* __restrict__ Tv, short* __restrict__ To)
{
    const int z = blockIdx.z;
    const float* W = z==0?Wq:(z==1?Wk:(z==2?Wv:Wo));
    short* T       = z==0?Tq:(z==1?Tk:(z==2?Tv:To));
    __shared__ short tile[64][65];
    const int k0 = blockIdx.y*64, n0 = blockIdx.x*64;
    const int t = threadIdx.x;
    const int kr = t>>4, nc = (t&15)*4;
    #pragma unroll
    for (int p=0;p<4;p++){
        int k = p*16 + kr;
        float4 w = *(const float4*)&W[(size_t)(k0+k)*D_ + n0 + nc];
        tile[k][nc+0]=f2bf(w.x); tile[k][nc+1]=f2bf(w.y);
        tile[k][nc+2]=f2bf(w.z); tile[k][nc+3]=f2bf(w.w);
    }
    __syncthreads();
    #pragma unroll
    for (int p=0;p<4;p++){
        int n = p*16 + kr;
        short4 o; o.x=tile[nc+0][n]; o.y=tile[nc+1][n]; o.z=tile[nc+2][n]; o.w=tile[nc+3][n];
        *(short4*)&T[(size_t)(n0+n)*D_ + k0 + nc] = o;
    }
}

// ---------- K1: QKV projections via MFMA. QB/KB: [bh][s][d]; V -> VT [bh][d][s] ----------
__global__ __launch_bounds__(256) void proj_mfma_kernel(
    const short* __restrict__ aq, const short* __restrict__ ak, const short* __restrict__ av,
    const short* __restrict__ Tq, const short* __restrict__ Tk, const short* __restrict__ Tv,
    const float* __restrict__ bq, const float* __restrict__ bk, const float* __restrict__ bv,
    short* __restrict__ QB, short* __restrict__ KB, short* __restrict__ VTB)
{
    const int z = blockIdx.z;
    const short* A  = z==0?aq:(z==1?ak:av);
    const short* WT = z==0?Tq:(z==1?Tk:Tv);
    const float* bias = z==0?bq:(z==1?bk:bv);
    __shared__ short As[128][72];
    __shared__ short Bs[64][72];
    const int tid = threadIdx.x;
    const int w = tid>>6, lane = tid&63, g = lane>>4, r16 = lane&15;
    const int m0 = blockIdx.y*128, h = blockIdx.x, n0 = h*64;
    f32x4 acc[2][4] = {};
    for (int kc=0; kc<12; ++kc){
        {
            int row = tid>>1, half = tid&1;
            const uint4* src = (const uint4*)&A[(size_t)(m0+row)*D_ + kc*64 + half*32];
            uint4* dst = (uint4*)&As[row][half*32];
            dst[0]=src[0]; dst[1]=src[1]; dst[2]=src[2]; dst[3]=src[3];
        }
        if (tid < 128){
            int row = tid>>1, half = tid&1;
            const uint4* src = (const uint4*)&WT[(size_t)(n0+row)*D_ + kc*64 + half*32];
            uint4* dst = (uint4*)&Bs[row][half*32];
            dst[0]=src[0]; dst[1]=src[1]; dst[2]=src[2]; dst[3]=src[3];
        }
        __syncthreads();
        #pragma unroll
        for (int ks=0; ks<2; ++ks){
            bf16x8 a0 = *(const bf16x8*)&As[w*32      + r16][ks*32 + g*8];
            bf16x8 a1 = *(const bf16x8*)&As[w*32 + 16 + r16][ks*32 + g*8];
            #pragma unroll
            for (int ni=0; ni<4; ++ni){
                bf16x8 b = *(const bf16x8*)&Bs[ni*16 + r16][ks*32 + g*8];
                acc[0][ni] = MFMA16(a0, b, acc[0][ni]);
                acc[1][ni] = MFMA16(a1, b, acc[1][ni]);
            }
        }
        __syncthreads();
    }
    #pragma unroll
    for (int mi=0; mi<2; ++mi)
    #pragma unroll
    for (int ni=0; ni<4; ++ni)
    #pragma unroll
    for (int r=0; r<4; ++r){
        int m = m0 + w*32 + mi*16 + g*4 + r;
        int b = m>>10, s = m&1023;
        int d = ni*16 + r16;
        short o = f2bf(acc[mi][ni][r] + bias[n0 + d]);
        if (z==2) VTB[(((size_t)b*H_ + h)*DH_ + d)*S_ + s] = o;
        else {
            short* dst = (z==0) ? QB : KB;
            dst[(((size_t)b*H_ + h)*S_ + s)*DH_ + d] = o;
        }
    }
}

// ---------- K2: raw scores = Q @ K^T per bh (MFMA) -> WEI fp32 ----------
__global__ __launch_bounds__(256) void qk_mfma_kernel(
    const short* __restrict__ QB, const short* __restrict__ KB, float* __restrict__ sc)
{
    const int bh = blockIdx.z;
    const short* Q = QB + (size_t)bh*S_*DH_;
    const short* K = KB + (size_t)bh*S_*DH_;
    __shared__ short Qs[128][72];
    __shared__ short Ks[128][72];
    const int tid = threadIdx.x;
    const int w = tid>>6, lane = tid&63, g = lane>>4, r16 = lane&15;
    const int j0 = blockIdx.y*128, k0 = blockIdx.x*128;
    {
        int row = tid>>1, half = tid&1;
        const uint4* sq = (const uint4*)&Q[(size_t)(j0+row)*DH_ + half*32];
        uint4* dq = (uint4*)&Qs[row][half*32];
        dq[0]=sq[0]; dq[1]=sq[1]; dq[2]=sq[2]; dq[3]=sq[3];
        const uint4* sk = (const uint4*)&K[(size_t)(k0+row)*DH_ + half*32];
        uint4* dk = (uint4*)&Ks[row][half*32];
        dk[0]=sk[0]; dk[1]=sk[1]; dk[2]=sk[2]; dk[3]=sk[3];
    }
    __syncthreads();
    f32x4 acc[2][8] = {};
    #pragma unroll
    for (int ks=0; ks<2; ++ks){
        bf16x8 a0 = *(const bf16x8*)&Qs[w*32      + r16][ks*32 + g*8];
        bf16x8 a1 = *(const bf16x8*)&Qs[w*32 + 16 + r16][ks*32 + g*8];
        #pragma unroll
        for (int ni=0; ni<8; ++ni){
            bf16x8 b = *(const bf16x8*)&Ks[ni*16 + r16][ks*32 + g*8];
            acc[0][ni] = MFMA16(a0, b, acc[0][ni]);
            acc[1][ni] = MFMA16(a1, b, acc[1][ni]);
        }
    }
    float* srow = sc + (size_t)bh*S_*S_;
    #pragma unroll
    for (int mi=0; mi<2; ++mi)
    #pragma unroll
    for (int ni=0; ni<8; ++ni)
    #pragma unroll
    for (int r=0; r<4; ++r){
        int j = j0 + w*32 + mi*16 + g*4 + r;
        int k = k0 + ni*16 + r16;
        srow[(size_t)j*S_ + k] = acc[mi][ni][r];
    }
}

// ---------- K3: fused per-j  bias + softmax + pos-ctx ----------
__global__ __launch_bounds__(512) void fused_j_kernel(
    const float* __restrict__ pos, const short* __restrict__ QB,
    const float* __restrict__ mask, float* __restrict__ WEI, short* __restrict__ PBIAS)
{
    const int j = blockIdx.x;
    const int tid = threadIdx.x;
    const int w = tid>>6, lane = tid&63, g = lane>>4, r16 = lane&15;
    const int mi = w>>2, ni = w&3;
    __shared__ short SB[24][1032];     // scores/weights bf16
    __shared__ short Pt[2][64][72];    // pos chunk staging (dbuf)
    __shared__ short Qs[32][72];       // Q rows, zero-padded to 32

    // ===== Phase B prologue: issue 3-deep ring loads (chunks 0..2) =====
    const int klB0 = tid>>4, f4B = tid&15;   // k-local row / d-float4
    const int klB1 = klB0 + 32;
    float4 sA[3], sB[3];
    #pragma unroll
    for (int s=0; s<3; ++s){
        sA[s] = *(const float4*)&pos[((size_t)(s*64+klB0)*S_ + j)*DH_ + f4B*4];
        sB[s] = *(const float4*)&pos[((size_t)(s*64+klB1)*S_ + j)*DH_ + f4B*4];
    }

    // Phase A: raw scores fp32 -> SB bf16 ; stage Qs (full rows)
    for (int t = tid; t < 24*256; t += 512){
        int bh = t>>8, f4 = t&255;
        float4 x = *(const float4*)&WEI[((size_t)bh*S_ + j)*S_ + f4*4];
        *(short4*)&SB[bh][f4*4] = cvt4(x);
    }
    if (tid < 256){
        int row = tid>>3, q4 = tid&7;
        uint4 v = {0,0,0,0};
        if (row < BH_) v = *(const uint4*)&QB[((size_t)row*S_ + j)*DH_ + q4*8];
        *(uint4*)&Qs[row][q4*8] = v;
    }
    // write chunk 0 to Pt[0]; reissue slot0 <- chunk 3
    *(short4*)&Pt[0][klB0][f4B*4] = cvt4(sA[0]);
    *(short4*)&Pt[0][klB1][f4B*4] = cvt4(sB[0]);
    sA[0] = *(const float4*)&pos[((size_t)(3*64+klB0)*S_ + j)*DH_ + f4B*4];
    sB[0] = *(const float4*)&pos[((size_t)(3*64+klB1)*S_ + j)*DH_ + f4B*4];
    __syncthreads();

    // hoisted Q fragments (constant over chunks)
    bf16x8 aB0 = *(const bf16x8*)&Qs[mi*16 + r16][g*8];
    bf16x8 aB1 = *(const bf16x8*)&Qs[mi*16 + r16][32 + g*8];

    // ===== Phase B loop: SB[bh][k] += Q·pos^T, 16 chunks, 1 barrier each =====
    #pragma unroll
    for (int kc=0; kc<16; ++kc){
        const int cur = kc&1;
        f32x4 acc = {0.f,0.f,0.f,0.f};
        acc = MFMA16(aB0, *(const bf16x8*)&Pt[cur][ni*16 + r16][g*8],      acc);
        acc = MFMA16(aB1, *(const bf16x8*)&Pt[cur][ni*16 + r16][32 + g*8], acc);
        #pragma unroll
        for (int r=0; r<4; ++r){
            int bh = mi*16 + g*4 + r;
            if (bh < BH_){
                int col = kc*64 + ni*16 + r16;
                SB[bh][col] = f2bf(bf2f(SB[bh][col]) + acc[r]);
            }
        }
        if (kc < 15){
            const int s = (kc+1)%3;
            *(short4*)&Pt[cur^1][klB0][f4B*4] = cvt4(sA[s]);
            *(short4*)&Pt[cur^1][klB1][f4B*4] = cvt4(sB[s]);
            if (kc+4 < 16){
                sA[s] = *(const float4*)&pos[((size_t)((kc+4)*64+klB0)*S_ + j)*DH_ + f4B*4];
                sB[s] = *(const float4*)&pos[((size_t)((kc+4)*64+klB1)*S_ + j)*DH_ + f4B*4];
            }
        }
        __syncthreads();
    }

    // ===== Phase D ring loads issued early (hidden under softmax) =====
    // mapping: k = lane (one 16B read per lane), dblk = w (i=0) / w+8 (i=1)
    #pragma unroll
    for (int s=0; s<3; ++s){
        sA[s] = *(const float4*)&pos[((size_t)j*S_ + s*64 + lane)*DH_ + w*4];
        sB[s] = *(const float4*)&pos[((size_t)j*S_ + s*64 + lane)*DH_ + (w+8)*4];
    }

    // ===== Phase C: softmax rows (wave w owns bh = w, w+8, w+16) =====
    #pragma unroll
    for (int rr=0; rr<3; ++rr){
        int bh = w + rr*8;
        const float* mrow = mask + (size_t)(bh/H_)*S_;
        float x[16];
        #pragma unroll
        for (int i=0;i<16;++i)
            x[i] = bf2f(SB[bh][i*64 + lane])*0.125f + mrow[i*64+lane]*(-1e9f);
        float mx = x[0];
        #pragma unroll
        for (int i=1;i<16;++i) mx = fmaxf(mx, x[i]);
        #pragma unroll
        for (int off=32; off>0; off>>=1) mx = fmaxf(mx, __shfl_xor(mx, off, 64));
        float sm = 0.f;
        #pragma unroll
        for (int i=0;i<16;++i){ x[i] = __expf(x[i]-mx); sm += x[i]; }
        #pragma unroll
        for (int off=32; off>0; off>>=1) sm += __shfl_xor(sm, off, 64);
        float inv = 1.0f / sm;
        float* wrow = &WEI[((size_t)bh*S_ + j)*S_];
        #pragma unroll
        for (int i=0;i<16;++i){
            float wt = x[i]*inv;
            wrow[i*64+lane] = wt;
            SB[bh][i*64+lane] = f2bf(wt);
        }
    }
    __syncthreads();   // SB weights complete before Phase D reads

    // quad-transpose write: lane holds float4 P[k=lane][dblk*4..+3]; after 4x4
    // transpose across lane quads, writes short4 along k -> Pt[buf][d][k] 2-way free.
    auto qtwrite = [&](float4 v, int dblk, int buf){
        unsigned A = pack2(f2bf(v.x), f2bf(v.y));
        unsigned Bu = pack2(f2bf(v.z), f2bf(v.w));
        unsigned X = __shfl_xor(A, 1, 64), Y = __shfl_xor(Bu, 1, 64);
        bool odd = lane & 1;
        unsigned A2 = odd ? ((X>>16)|(A &0xFFFF0000u)) : ((A &0xFFFFu)|(X<<16));
        unsigned B2 = odd ? ((Y>>16)|(Bu&0xFFFF0000u)) : ((Bu&0xFFFFu)|(Y<<16));
        unsigned Z  = __shfl_xor(A2, 2, 64), W2 = __shfl_xor(B2, 2, 64);
        bool hi = lane & 2;
        uint2 o; o.x = hi ? W2 : A2; o.y = hi ? B2 : Z;
        int row = dblk*4 + (lane&3);
        int col = (lane>>2)*4;
        *(uint2*)&Pt[buf][row][col] = o;
    };

    // write chunk 0 (transposed) to Pt[0]; reissue slot0 <- chunk 3
    qtwrite(sA[0], w,     0);
    qtwrite(sB[0], w + 8, 0);
    sA[0] = *(const float4*)&pos[((size_t)j*S_ + 3*64 + lane)*DH_ + w*4];
    sB[0] = *(const float4*)&pos[((size_t)j*S_ + 3*64 + lane)*DH_ + (w+8)*4];
    __syncthreads();

    // ===== Phase D loop: PBIAS = W @ pos_j, 16 chunks, 1 barrier each =====
    const int arow_base = (mi==0) ? 0 : 8;   // overlapping m-tiles {0-15, 8-23}
    f32x4 dacc = {0.f,0.f,0.f,0.f};
    #pragma unroll
    for (int kc=0; kc<16; ++kc){
        const int cur = kc&1;
        #pragma unroll
        for (int ks=0; ks<2; ++ks){
            bf16x8 a = *(const bf16x8*)&SB[arow_base + r16][kc*64 + ks*32 + g*8];
            bf16x8 b = *(const bf16x8*)&Pt[cur][ni*16 + r16][ks*32 + g*8];
            dacc = MFMA16(a, b, dacc);
        }
        if (kc < 15){
            const int s = (kc+1)%3;
            qtwrite(sA[s], w,     cur^1);
            qtwrite(sB[s], w + 8, cur^1);
            if (kc+4 < 16){
                sA[s] = *(const float4*)&pos[((size_t)j*S_ + (kc+4)*64 + lane)*DH_ + w*4];
                sB[s] = *(const float4*)&pos[((size_t)j*S_ + (kc+4)*64 + lane)*DH_ + (w+8)*4];
            }
        }
        __syncthreads();
    }

    #pragma unroll
    for (int r=0; r<4; ++r){
        int bh = arow_base + g*4 + r;
        bool keep = (mi==0) ? (bh < 16) : (bh >= 16);
        if (keep){
            int d = ni*16 + r16;
            size_t o = ((size_t)(bh/H_)*S_ + j)*D_ + (bh%H_)*DH_ + d;
            PBIAS[o] = f2bf(dacc[r]);
        }
    }
}

// ---------- K4: ctx = W @ V per bh via MFMA, + PBIAS -> CTXB bf16 ----------
__global__ __launch_bounds__(256) void wv_mfma_kernel(
    const float* __restrict__ sc, const short* __restrict__ VTB,
    const short* __restrict__ PBIAS, short* __restrict__ CTXB)
{
    const int bh = blockIdx.y, m0 = blockIdx.x*64;
    const float* W  = sc  + (size_t)bh*S_*S_;
    const short* VT = VTB + (size_t)bh*DH_*S_;
    __shared__ short Ws[64][72];
    __shared__ short Vs[64][72];
    const int tid = threadIdx.x;
    const int w = tid>>6, lane = tid&63, g = lane>>4, r16 = lane&15;
    f32x4 acc[4] = {};
    for (int kc=0; kc<16; ++kc){
        if (tid < 128){
            int row = tid>>1, half = tid&1;
            const float* src = &W[(size_t)(m0+row)*S_ + kc*64 + half*32];
            uint4* dst = (uint4*)&Ws[row][half*32];
            #pragma unroll
            for (int i=0;i<4;i++){
                float4 x0 = *(const float4*)&src[i*8];
                float4 x1 = *(const float4*)&src[i*8+4];
                dst[i] = pack8(x0,x1);
            }
        } else {
            int t2 = tid-128;
            int row = t2>>1, half = t2&1;
            const uint4* src = (const uint4*)&VT[(size_t)row*S_ + kc*64 + half*32];
            uint4* dst = (uint4*)&Vs[row][half*32];
            dst[0]=src[0]; dst[1]=src[1]; dst[2]=src[2]; dst[3]=src[3];
        }
        __syncthreads();
        #pragma unroll
        for (int ks=0; ks<2; ++ks){
            bf16x8 a = *(const bf16x8*)&Ws[w*16 + r16][ks*32 + g*8];
            #pragma unroll
            for (int ni=0; ni<4; ++ni){
                bf16x8 b = *(const bf16x8*)&Vs[ni*16 + r16][ks*32 + g*8];
                acc[ni] = MFMA16(a, b, acc[ni]);
            }
        }
        __syncthreads();
    }
    const int b = bh/H_, h = bh%H_;
    #pragma unroll
    for (int ni=0; ni<4; ++ni)
    #pragma unroll
    for (int r=0; r<4; ++r){
        int jj = m0 + w*16 + g*4 + r;
        int d = ni*16 + r16;
        size_t o = ((size_t)b*S_ + jj)*D_ + h*DH_ + d;
        CTXB[o] = f2bf(acc[ni][r] + bf2f(PBIAS[o]));
    }
}

// ---------- K5: out = ctxb @ Wo + bo (MFMA) ----------
__global__ __launch_bounds__(256) void out_mfma_kernel(
    const short* __restrict__ CTXB, const short* __restrict__ To,
    const float* __restrict__ bo, float* __restrict__ outp)
{
    const int m0 = blockIdx.y*64, n0 = blockIdx.x*64;
    __shared__ short As[64][72];
    __shared__ short Bs[64][72];
    const int tid = threadIdx.x;
    const int w = tid>>6, lane = tid&63, g = lane>>4, r16 = lane&15;
    f32x4 acc[4] = {};
    for (int kc=0; kc<12; ++kc){
        if (tid < 128){
            int row = tid>>1, half = tid&1;
            const uint4* src = (const uint4*)&CTXB[(size_t)(m0+row)*D_ + kc*64 + half*32];
            uint4* dst = (uint4*)&As[row][half*32];
            dst[0]=src[0]; dst[1]=src[1]; dst[2]=src[2]; dst[3]=src[3];
        } else {
            int t2 = tid-128;
            int row = t2>>1, half = t2&1;
            const uint4* src = (const uint4*)&To[(size_t)(n0+row)*D_ + kc*64 + half*32];
            uint4* dst = (uint4*)&Bs[row][half*32];
            dst[0]=src[0]; dst[1]=src[1]; dst[2]=src[2]; dst[3]=src[3];
        }
        __syncthreads();
        #pragma unroll
        for (int ks=0; ks<2; ++ks){
            bf16x8 a = *(const bf16x8*)&As[w*16 + r16][ks*32 + g*8];
            #pragma unroll
            for (int ni=0; ni<4; ++ni){
                bf16x8 b = *(const bf16x8*)&Bs[ni*16 + r16][ks*32 + g*8];
                acc[ni] = MFMA16(a, b, acc[ni]);
            }
        }
        __syncthreads();
    }
    #pragma unroll
    for (int ni=0; ni<4; ++ni)
    #pragma unroll
    for (int r=0; r<4; ++r){
        int m = m0 + w*16 + g*4 + r;
        int n = n0 + ni*16 + r16;
        outp[(size_t)m*D_ + n] = acc[ni][r] + bo[n];
    }
}

extern "C" void kernel_launch(void* const* d_in, const int* in_sizes, int n_in,
                              void* d_out, int out_size, void* d_ws, size_t ws_size,
                              hipStream_t stream) {
    const float* q_in = (const float*)d_in[0];
    const float* k_in = (const float*)d_in[1];
    const float* v_in = (const float*)d_in[2];
    const float* pos  = (const float*)d_in[3];
    const float* mask = (const float*)d_in[4];
    const float* Wq   = (const float*)d_in[5];
    const float* bq   = (const float*)d_in[6];
    const float* Wk   = (const float*)d_in[7];
    const float* bk   = (const float*)d_in[8];
    const float* Wv   = (const float*)d_in[9];
    const float* bv   = (const float*)d_in[10];
    const float* Wo   = (const float*)d_in[11];
    const float* bo   = (const float*)d_in[12];

    float* outp = (float*)d_out;               // (B,S,D)
    float* WEI  = outp + OUTSZ_;               // (B,H,S,S) raw scores -> weights (in place per j)

    char* w8 = (char*)d_ws;
    short* QB  = (short*)w8;                                   // 3,145,728 B
    short* KB  = (short*)(w8 + 1*3145728);
    short* VTB = (short*)(w8 + 2*3145728);
    short* WTq = (short*)(w8 + 3*3145728);                     // 4 x 1,179,648 B
    short* WTk = WTq + 768*768;
    short* WTv = WTk + 768*768;
    short* WTo = WTv + 768*768;
    char*  r2  = w8 + 3*3145728 + 4*1179648;                   // 14,155,776
    short* AQ  = (short*)r2;                                   // 3 x 3,145,728 B (pre-proj)
    short* AK  = AQ + (size_t)2048*768;
    short* AV  = AK + (size_t)2048*768;
    short* PBIAS = (short*)r2;                                 // alias (post-proj): 3,145,728 B
    short* CTXB  = PBIAS + (size_t)B_*S_*D_;                   // 3,145,728 B

    cvt_in_kernel   <<<dim3(1536,3),   256, 0, stream>>>(q_in,k_in,v_in,AQ,AK,AV);
    wt_kernel       <<<dim3(12,12,4),  256, 0, stream>>>(Wq,Wk,Wv,Wo,WTq,WTk,WTv,WTo);
    proj_mfma_kernel<<<dim3(12,16,3),  256, 0, stream>>>(AQ,AK,AV,WTq,WTk,WTv,bq,bk,bv,QB,KB,VTB);
    qk_mfma_kernel  <<<dim3(8,8,24),   256, 0, stream>>>(QB,KB,WEI);
    fused_j_kernel  <<<dim3(1024),     512, 0, stream>>>(pos,QB,mask,WEI,PBIAS);
    wv_mfma_kernel  <<<dim3(16,24),    256, 0, stream>>>(WEI,VTB,PBIAS,CTXB);
    out_mfma_kernel <<<dim3(12,32),    256, 0, stream>>>(CTXB,WTo,bo,outp);
}